// Round 5
// baseline (240.448 us; speedup 1.0000x reference)
//
#include <hip/hip_runtime.h>

#define BATCH 4
#define CH    256
#define NTOK  4096
#define DQK   32

typedef __attribute__((ext_vector_type(4))) float  f32x4;
typedef __attribute__((ext_vector_type(2))) float  f32x2;
typedef __attribute__((ext_vector_type(8))) __bf16 bf16x8;
typedef __attribute__((ext_vector_type(2))) unsigned int u32x2;
typedef __attribute__((ext_vector_type(4))) unsigned int u32x4;

// round-to-nearest-even float -> bf16 bits (cold paths)
static __device__ __forceinline__ unsigned short f2bf(float f) {
    unsigned int u = __builtin_bit_cast(unsigned int, f);
    unsigned int r = u + 0x7FFFu + ((u >> 16) & 1u);
    return (unsigned short)(r >> 16);
}
static __device__ __forceinline__ unsigned int pack2(float a, float b) {
    return (unsigned int)f2bf(a) | ((unsigned int)f2bf(b) << 16);
}
// hot-path pack: single HW instr, RTNE, a->lo b->hi
static __device__ __forceinline__ unsigned int cvt_pk_bf16(float a, float b) {
    unsigned int r;
    asm("v_cvt_pk_bf16_f32 %0, %1, %2" : "=v"(r) : "v"(a), "v"(b));
    return r;
}

// ---------------------------------------------------------------------------
// Kernel 0: convert Wq|Wk|Wv -> Wbf [320 rows][256 c] bf16; zero Mk scalars.
// ---------------------------------------------------------------------------
__global__ __launch_bounds__(256)
void wconv(const float* __restrict__ Wq, const float* __restrict__ Wk,
           const float* __restrict__ Wv, unsigned short* __restrict__ Wbf,
           unsigned int* __restrict__ Mk)
{
    if (blockIdx.x == 0 && threadIdx.x < BATCH) Mk[threadIdx.x] = 0u;
    const int id = (blockIdx.x * 256 + threadIdx.x) * 4;
    const int r  = id >> 8;
    const int c  = id & 255;
    const float* src = (r < 32) ? (Wq + r * 256 + c)
                     : (r < 64) ? (Wk + (r - 32) * 256 + c)
                                : (Wv + (size_t)(r - 64) * 256 + c);
    float v0 = src[0], v1 = src[1], v2 = src[2], v3 = src[3];
    u32x2 p = {pack2(v0, v1), pack2(v2, v3)};
    *reinterpret_cast<u32x2*>(Wbf + id) = p;
}

// ---------------------------------------------------------------------------
// Kernel 1: QKV projection, barrier-free main loop. 16-token blocks (grid
// 1024 = 4 blocks/CU = 16 waves/CU). Pack via v_cvt_pk_bf16_f32.
// ---------------------------------------------------------------------------
__global__ __launch_bounds__(256, 4)
void qkv_proj(const float* __restrict__ x,
              const float* __restrict__ pbq, const float* __restrict__ pbk,
              const float* __restrict__ pbv,
              const unsigned short* __restrict__ Wbf,
              unsigned short* __restrict__ Qh,
              unsigned short* __restrict__ Kh,
              unsigned short* __restrict__ Vh,
              unsigned int* __restrict__ Mk)
{
    const int t    = threadIdx.x;
    const int wave = t >> 6;
    const int lane = t & 63;
    const int low  = lane & 15;
    const int quad = lane >> 4;
    const int tok0 = blockIdx.x * 16;
    const int b    = tok0 >> 12;
    const int nl0  = tok0 & (NTOK - 1);

    __shared__ unsigned short ob[256 * 24];     // V transpose [c][24]

    f32x4 acc[5];
    #pragma unroll
    for (int j = 0; j < 5; ++j) {
        const int rtg = wave * 5 + j;
        float bb = (rtg < 2) ? pbq[rtg * 16 + low]
                 : (rtg < 4) ? pbk[(rtg - 2) * 16 + low]
                             : pbv[(rtg - 4) * 16 + low];
        f32x4 z = {bb, bb, bb, bb};
        acc[j] = z;
    }

    const float* xb = x + (size_t)b * CH * NTOK + nl0 + low;

    #pragma unroll
    for (int k0 = 0; k0 < 8; ++k0) {
        const int cbase = k0 * 32 + quad * 8;
        float xv[8];
        #pragma unroll
        for (int e = 0; e < 8; ++e)
            xv[e] = xb[(size_t)(cbase + e) * NTOK];
        u32x4 ap = {cvt_pk_bf16(xv[0], xv[1]), cvt_pk_bf16(xv[2], xv[3]),
                    cvt_pk_bf16(xv[4], xv[5]), cvt_pk_bf16(xv[6], xv[7])};
        const bf16x8 af = __builtin_bit_cast(bf16x8, ap);
        #pragma unroll
        for (int j = 0; j < 5; ++j) {
            const int rtg = wave * 5 + j;
            const bf16x8 bf = *reinterpret_cast<const bf16x8*>(
                Wbf + (size_t)(rtg * 16 + low) * 256 + k0 * 32 + quad * 8);
            acc[j] = __builtin_amdgcn_mfma_f32_16x16x32_bf16(af, bf, acc[j], 0, 0, 0);
        }
    }

    // ---- Q/K epilogue + ||k||^2 max (wave 0: rtg 0..3) ----
    #pragma unroll
    for (int j = 0; j < 5; ++j) {
        const int rtg = wave * 5 + j;
        if (rtg < 4) {
            unsigned short* dst = (rtg < 2) ? Qh : Kh;
            const int wr = (rtg & 1) * 16 + low;
            #pragma unroll
            for (int reg = 0; reg < 4; ++reg) {
                const int token = tok0 + quad * 4 + reg;
                dst[(size_t)token * DQK + wr] = f2bf(acc[j][reg]);
            }
        }
    }
    if (wave == 0) {
        f32x4 kk = acc[2] * acc[2] + acc[3] * acc[3];
        #pragma unroll
        for (int mask = 1; mask <= 8; mask <<= 1)
            #pragma unroll
            for (int reg = 0; reg < 4; ++reg)
                kk[reg] += __shfl_xor(kk[reg], mask);
        if (low == 0) {
            #pragma unroll
            for (int reg = 0; reg < 4; ++reg)
                atomicMax(&Mk[b], __builtin_bit_cast(unsigned int, kk[reg]));
        }
    }

    // ---- V epilogue: transpose via LDS (ordered by __syncthreads) ----
    #pragma unroll
    for (int j = 0; j < 5; ++j) {
        const int rtg = wave * 5 + j;
        if (rtg >= 4) {
            const int c = (rtg - 4) * 16 + low;
            #pragma unroll
            for (int reg = 0; reg < 4; ++reg)
                ob[c * 24 + quad * 4 + reg] = f2bf(acc[j][reg]);
        }
    }
    __syncthreads();
    {
        const unsigned int* obd = (const unsigned int*)ob;
        const int h = t & 1;
        #pragma unroll
        for (int pass = 0; pass < 2; ++pass) {
            const int c = (t >> 1) + pass * 128;
            const u32x4 v = *reinterpret_cast<const u32x4*>(obd + c * 12 + h * 4);
            *reinterpret_cast<u32x4*>(
                Vh + ((size_t)b * CH + c) * NTOK + nl0 + h * 8) = v;
        }
    }
}

// ---------------------------------------------------------------------------
// Kernel 2: flash attention, barrier-free main loop, wave-private P.
// R4 root-cause: P was WRITTEN as u32x2 but READ as bf16x8 — distinct TBAA
// classes, so -O3 strict aliasing let the compiler hoist PV's ds_reads above
// S_SOFTMAX's ds_writes to the SAME buffer across the iteration boundary.
// R0/R1 were saved by per-iter __syncthreads; the R2-bench barrier-free
// version survived on schedule luck; the reorder broke it (absmax 43/46,
// schedule-dependent — stride was never the culprit).
// Fix: (a) PV reads P as u32x4 (same TBAA class as writes) + bit_cast to
// bf16x8 (bitwise identical fragment); (b) sched_barrier(0) after each
// S_SOFTMAX pins the write->next-read boundary. Reorder kept:
// LOAD_KF(i+1); PV(i); S_SOFTMAX(i+1) — kf L2 latency hides under PV issue.
// ---------------------------------------------------------------------------
__global__ __launch_bounds__(512, 2)
void attn(const float* __restrict__ x,
          const unsigned short* __restrict__ Qh,
          const unsigned short* __restrict__ Kh,
          const unsigned short* __restrict__ Vh,
          const unsigned int* __restrict__ Mk,
          float* __restrict__ out)
{
    const int t    = threadIdx.x;
    const int wave = t >> 6;                 // 0..7
    const int kg   = wave & 3;               // keygroup
    const int ch   = wave >> 2;              // channel half (PV only)
    const int lane = t & 63;
    const int low  = lane & 15;
    const int quad = lane >> 4;

    const int beta = blockIdx.x;             // XCD swizzle (perf heuristic)
    const int b    = (beta & 7) >> 1;
    const int q0   = (((beta >> 3) * 2) + (beta & 1)) * 64;

    // dwords: [0,36864) private P, dbuf: buf*18432 + wave*2304 + row*36;
    // [36864,37120) lbuf. Merge slabs (8 x 1408 dw) alias Pbuf0+ (after
    // the post-loop barrier only).
    __shared__ float smem[36864 + 256];
    unsigned int* Pbase = (unsigned int*)smem;
    float* lbuf = smem + 36864;

    const float LOG2E = 1.44269504088896f;

    bf16x8 qfrag[4];
    float  m2[4];
    {
        const float M2 = __builtin_bit_cast(float, Mk[b]);
        #pragma unroll
        for (int j = 0; j < 4; ++j) {
            qfrag[j] = *reinterpret_cast<const bf16x8*>(
                Qh + (size_t)(b * NTOK + q0 + j * 16 + low) * DQK + quad * 8);
            float qn2 = 0.f;
            #pragma unroll
            for (int e = 0; e < 8; ++e) {
                float qv = (float)qfrag[j][e];
                qn2 += qv * qv;
            }
            qn2 += __shfl_xor(qn2, 16);
            qn2 += __shfl_xor(qn2, 32);
            m2[j] = __builtin_sqrtf(qn2 * M2) * (1.02f * LOG2E);
        }
    }

    f32x4 acc[4][8];
    #pragma unroll
    for (int qs = 0; qs < 4; ++qs)
        #pragma unroll
        for (int ct = 0; ct < 8; ++ct) { f32x4 z = {0.f,0.f,0.f,0.f}; acc[qs][ct] = z; }
    float l_s[4] = {0.f, 0.f, 0.f, 0.f};

    const unsigned short* Kb = Kh + (size_t)b * NTOK * DQK;
    const unsigned short* Vb = Vh + (size_t)b * CH * NTOK;

    bf16x8 kf[4];

    #define LOAD_KF(ii)                                                         \
    {                                                                           \
        const int n0s = ((ii) * 4 + kg) * 64;                                   \
        _Pragma("unroll")                                                       \
        for (int kt = 0; kt < 4; ++kt)                                          \
            kf[kt] = *reinterpret_cast<const bf16x8*>(                          \
                Kb + (size_t)(n0s + kt * 16 + low) * DQK + quad * 8);           \
    }

    // S-MFMA (from preloaded kf) + exp2 + pack + write to buf, all 4 qs.
    // Trailing sched_barrier(0): no LDS op (esp. next PV's ds_reads) may be
    // scheduled across the P writes.
    #define S_SOFTMAX(buf)                                                      \
    {                                                                           \
        unsigned int* pqb = Pbase + (buf) * 18432 + wave * 2304;                \
        _Pragma("unroll")                                                       \
        for (int j = 0; j < 4; ++j) {                                           \
            f32x4 S[4];                                                         \
            _Pragma("unroll")                                                   \
            for (int kt = 0; kt < 4; ++kt) {                                    \
                f32x4 z = {0.f,0.f,0.f,0.f};                                    \
                S[kt] = __builtin_amdgcn_mfma_f32_16x16x32_bf16(kf[kt],         \
                            qfrag[j], z, 0, 0, 0);                              \
            }                                                                   \
            float sum = 0.f;                                                    \
            unsigned int* pq = pqb + (j * 16 + low) * 36 + quad * 2;            \
            _Pragma("unroll")                                                   \
            for (int kt = 0; kt < 4; ++kt) {                                    \
                float p0 = __builtin_amdgcn_exp2f(S[kt][0] * LOG2E - m2[j]);    \
                float p1 = __builtin_amdgcn_exp2f(S[kt][1] * LOG2E - m2[j]);    \
                float p2 = __builtin_amdgcn_exp2f(S[kt][2] * LOG2E - m2[j]);    \
                float p3 = __builtin_amdgcn_exp2f(S[kt][3] * LOG2E - m2[j]);    \
                sum += (p0 + p1) + (p2 + p3);                                   \
                u32x2 w2 = {cvt_pk_bf16(p0, p1), cvt_pk_bf16(p2, p3)};          \
                *reinterpret_cast<u32x2*>(pq + kt * 8) = w2;                    \
            }                                                                   \
            l_s[j] += sum;                                                      \
        }                                                                       \
        __builtin_amdgcn_sched_barrier(0);                                      \
    }

    LOAD_KF(0)
    S_SOFTMAX(0)

    for (int i = 0; i < 16; ++i) {
        // kf(i+1) issued EARLY: L2 latency hides under PV(i)'s MFMA issue.
        if (i < 15) LOAD_KF(i + 1)

        // ---- PV(i) from own Pbuf[i&1]; P read as u32x4 (same TBAA class
        //      as the u32x2 writes) then bit_cast to the MFMA fragment ----
        {
            const int n0 = (i * 4 + kg) * 64;
            const unsigned int* Pd = Pbase + (i & 1) * 18432 + wave * 2304;
            __builtin_amdgcn_s_setprio(1);
            #pragma unroll
            for (int s = 0; s < 2; ++s) {
                bf16x8 pf[4];
                #pragma unroll
                for (int qs = 0; qs < 4; ++qs) {
                    const u32x4 pw = *reinterpret_cast<const u32x4*>(
                        Pd + (qs * 16 + low) * 36 + s * 16 + quad * 4);
                    pf[qs] = __builtin_bit_cast(bf16x8, pw);
                }
                #pragma unroll
                for (int ct = 0; ct < 8; ++ct) {
                    const bf16x8 vf = *reinterpret_cast<const bf16x8*>(
                        Vb + (size_t)(ch * 128 + ct * 16 + low) * NTOK
                           + n0 + s * 32 + quad * 8);
                    #pragma unroll
                    for (int qs = 0; qs < 4; ++qs)
                        acc[qs][ct] = __builtin_amdgcn_mfma_f32_16x16x32_bf16(
                            vf, pf[qs], acc[qs][ct], 0, 0, 0);
                }
            }
            __builtin_amdgcn_s_setprio(0);
        }

        // ---- S(i+1) + softmax into buf^1 (kf already resident) ----
        if (i < 15) S_SOFTMAX((i + 1) & 1)
    }
    #undef LOAD_KF
    #undef S_SOFTMAX

    // ---- publish per-keygroup l (each wave computed all 4; publish own 2) ----
    #pragma unroll
    for (int j = 0; j < 4; ++j) {
        l_s[j] += __shfl_xor(l_s[j], 16);
        l_s[j] += __shfl_xor(l_s[j], 32);
    }
    if (quad == 0) {
        #pragma unroll
        for (int jj = 0; jj < 2; ++jj) {
            const int qs = 2 * ch + jj;
            lbuf[kg * 64 + qs * 16 + low] = l_s[qs];
        }
    }
    __syncthreads();   // waves may have drifted; all must be done with P

    // ---- merge 4 kg-partials, 32 channels (16 per ch-half) per round ----
    const int q = t & 63;
    const int u = t >> 6;                    // 0..7
    float invl = 0.f;
    for (int rd = 0; rd < 8; ++rd) {
        #pragma unroll
        for (int qs = 0; qs < 4; ++qs) {
            float* sl = smem + wave * 1408 + (qs * 16 + low) * 22 + quad * 4;
            f32x2 lo = {acc[qs][rd][0], acc[qs][rd][1]};
            f32x2 hi = {acc[qs][rd][2], acc[qs][rd][3]};
            *reinterpret_cast<f32x2*>(sl)     = lo;
            *reinterpret_cast<f32x2*>(sl + 2) = hi;
        }
        __syncthreads();
        if (rd == 0)
            invl = 1.0f / (((lbuf[q] + lbuf[64 + q]) + (lbuf[128 + q] + lbuf[192 + q])));

        #pragma unroll
        for (int p = 0; p < 4; ++p) {
            const int half = p >> 1;
            const int c15  = u * 2 + (p & 1);            // 0..15
            const int wb   = half * 4;
            float O = (smem[(wb + 0) * 1408 + q * 22 + c15]
                     + smem[(wb + 1) * 1408 + q * 22 + c15])
                    + (smem[(wb + 2) * 1408 + q * 22 + c15]
                     + smem[(wb + 3) * 1408 + q * 22 + c15]);
            const int c = half * 128 + rd * 16 + c15;
            const size_t idx = (size_t)(b * CH + c) * NTOK + q0 + q;
            out[idx] = x[idx] + O * invl;
        }
        __syncthreads();
    }
}

extern "C" void kernel_launch(void* const* d_in, const int* in_sizes, int n_in,
                              void* d_out, int out_size, void* d_ws, size_t ws_size,
                              hipStream_t stream) {
    const float* x  = (const float*)d_in[0];
    const float* Wq = (const float*)d_in[1];
    const float* bq = (const float*)d_in[2];
    const float* Wk = (const float*)d_in[3];
    const float* bk = (const float*)d_in[4];
    const float* Wv = (const float*)d_in[5];
    const float* bv = (const float*)d_in[6];
    float* out = (float*)d_out;

    unsigned short* Qh  = (unsigned short*)d_ws;                 // [B,N,32] bf16
    unsigned short* Kh  = Qh  + (size_t)BATCH * NTOK * DQK;      // [B,N,32] bf16
    unsigned short* Vh  = Kh  + (size_t)BATCH * NTOK * DQK;      // [B,C,N] bf16
    unsigned short* Wbf = Vh  + (size_t)BATCH * CH * NTOK;       // [320,256] bf16
    unsigned int*   Mk  = (unsigned int*)(Wbf + 320 * 256);      // [B] max||k||^2

    wconv<<<dim3(80), dim3(256), 0, stream>>>(Wq, Wk, Wv, Wbf, Mk);
    qkv_proj<<<dim3(1024), dim3(256), 0, stream>>>(x, bq, bk, bv, Wbf,
                                                   Qh, Kh, Vh, Mk);
    attn<<<dim3(256), dim3(512), 0, stream>>>(x, Qh, Kh, Vh, Mk, out);
}

// Round 8
// 214.300 us; speedup vs baseline: 1.1220x; 1.1220x over previous
//
#include <hip/hip_runtime.h>

#define BATCH 4
#define CH    256
#define NTOK  4096
#define DQK   32

typedef __attribute__((ext_vector_type(4))) float  f32x4;
typedef __attribute__((ext_vector_type(2))) float  f32x2;
typedef __attribute__((ext_vector_type(8))) __bf16 bf16x8;
typedef __attribute__((ext_vector_type(2))) unsigned int u32x2;
typedef __attribute__((ext_vector_type(4))) unsigned int u32x4;

// round-to-nearest-even float -> bf16 bits (cold paths)
static __device__ __forceinline__ unsigned short f2bf(float f) {
    unsigned int u = __builtin_bit_cast(unsigned int, f);
    unsigned int r = u + 0x7FFFu + ((u >> 16) & 1u);
    return (unsigned short)(r >> 16);
}
static __device__ __forceinline__ unsigned int pack2(float a, float b) {
    return (unsigned int)f2bf(a) | ((unsigned int)f2bf(b) << 16);
}
// hot-path pack: single HW instr, RTNE, a->lo b->hi
static __device__ __forceinline__ unsigned int cvt_pk_bf16(float a, float b) {
    unsigned int r;
    asm("v_cvt_pk_bf16_f32 %0, %1, %2" : "=v"(r) : "v"(a), "v"(b));
    return r;
}

// ---------------------------------------------------------------------------
// Kernel 0: convert Wq|Wk|Wv -> Wbf [320 rows][256 c] bf16; zero Mk scalars.
// ---------------------------------------------------------------------------
__global__ __launch_bounds__(256)
void wconv(const float* __restrict__ Wq, const float* __restrict__ Wk,
           const float* __restrict__ Wv, unsigned short* __restrict__ Wbf,
           unsigned int* __restrict__ Mk)
{
    if (blockIdx.x == 0 && threadIdx.x < BATCH) Mk[threadIdx.x] = 0u;
    const int id = (blockIdx.x * 256 + threadIdx.x) * 4;
    const int r  = id >> 8;
    const int c  = id & 255;
    const float* src = (r < 32) ? (Wq + r * 256 + c)
                     : (r < 64) ? (Wk + (r - 32) * 256 + c)
                                : (Wv + (size_t)(r - 64) * 256 + c);
    float v0 = src[0], v1 = src[1], v2 = src[2], v3 = src[3];
    u32x2 p = {pack2(v0, v1), pack2(v2, v3)};
    *reinterpret_cast<u32x2*>(Wbf + id) = p;
}

// ---------------------------------------------------------------------------
// Kernel 1: QKV projection with LDS-staged coalesced x reads. DECISIVE A/B
// this round: paired with the byte-identical R1-verified attn. If the build
// fails, THIS kernel is guilty; if it passes, it's exonerated + banked.
// 32-token blocks (grid 512 = 2/CU). Stage x[b][0:256][tok0:tok0+32] -> LDS
// bf16 [c][38] via 128B-contiguous dwordx4; fragments via transposed u16
// reads (stride 38 -> ~2-way banks); V transposed in re-aliased buffer
// (stride 36, 8B-aligned stores).
// ---------------------------------------------------------------------------
__global__ __launch_bounds__(256, 2)
void qkv_proj(const float* __restrict__ x,
              const float* __restrict__ pbq, const float* __restrict__ pbk,
              const float* __restrict__ pbv,
              const unsigned short* __restrict__ Wbf,
              unsigned short* __restrict__ Qh,
              unsigned short* __restrict__ Kh,
              unsigned short* __restrict__ Vh,
              unsigned int* __restrict__ Mk)
{
    const int t    = threadIdx.x;
    const int wave = t >> 6;
    const int lane = t & 63;
    const int low  = lane & 15;
    const int quad = lane >> 4;
    const int blk  = blockIdx.x;
    const int b    = blk >> 7;               // 128 blocks per batch
    const int tok0 = (blk & 127) * 32;

    __shared__ unsigned short xs[256 * 38];  // x^T tile bf16 [c][38]; V re-aliases

    // ---- stage x[b][:, tok0:tok0+32] -> xs (coalesced 128B segments) ----
    {
        const float* xg = x + (size_t)b * CH * NTOK + tok0;
        const int k  = t & 7;                // 4-token group
        const int c0 = t >> 3;               // 0..31
        #pragma unroll
        for (int p = 0; p < 8; ++p) {
            const int c = p * 32 + c0;
            const f32x4 v = *reinterpret_cast<const f32x4*>(
                xg + (size_t)c * NTOK + k * 4);
            unsigned int* dst = reinterpret_cast<unsigned int*>(xs + c * 38 + k * 4);
            dst[0] = cvt_pk_bf16(v[0], v[1]);
            dst[1] = cvt_pk_bf16(v[2], v[3]);
        }
    }

    // bias init: acc[j][tt], rows rtg = wave*5+j, token-tiles tt=0,1
    f32x4 acc[5][2];
    #pragma unroll
    for (int j = 0; j < 5; ++j) {
        const int rtg = wave * 5 + j;
        float bb = (rtg < 2) ? pbq[rtg * 16 + low]
                 : (rtg < 4) ? pbk[(rtg - 2) * 16 + low]
                             : pbv[(rtg - 4) * 16 + low];
        f32x4 z = {bb, bb, bb, bb};
        acc[j][0] = z; acc[j][1] = z;
    }

    __syncthreads();

    #pragma unroll
    for (int k0 = 0; k0 < 8; ++k0) {
        bf16x8 wf[5];
        #pragma unroll
        for (int j = 0; j < 5; ++j) {
            const int rtg = wave * 5 + j;
            wf[j] = *reinterpret_cast<const bf16x8*>(
                Wbf + (size_t)(rtg * 16 + low) * 256 + k0 * 32 + quad * 8);
        }
        #pragma unroll
        for (int tt = 0; tt < 2; ++tt) {
            // A fragment: token = tt*16+low, channels k0*32+quad*8+e
            const unsigned short* xsrc = xs + (k0 * 32 + quad * 8) * 38 + tt * 16 + low;
            unsigned int w0 = (unsigned int)xsrc[0 * 38] | ((unsigned int)xsrc[1 * 38] << 16);
            unsigned int w1 = (unsigned int)xsrc[2 * 38] | ((unsigned int)xsrc[3 * 38] << 16);
            unsigned int w2 = (unsigned int)xsrc[4 * 38] | ((unsigned int)xsrc[5 * 38] << 16);
            unsigned int w3 = (unsigned int)xsrc[6 * 38] | ((unsigned int)xsrc[7 * 38] << 16);
            u32x4 ap = {w0, w1, w2, w3};
            const bf16x8 af = __builtin_bit_cast(bf16x8, ap);
            #pragma unroll
            for (int j = 0; j < 5; ++j)
                acc[j][tt] = __builtin_amdgcn_mfma_f32_16x16x32_bf16(
                    af, wf[j], acc[j][tt], 0, 0, 0);
        }
    }

    // ---- Q/K epilogue ----
    #pragma unroll
    for (int j = 0; j < 5; ++j) {
        const int rtg = wave * 5 + j;
        if (rtg < 4) {
            unsigned short* dst = (rtg < 2) ? Qh : Kh;
            const int wr = (rtg & 1) * 16 + low;
            #pragma unroll
            for (int tt = 0; tt < 2; ++tt)
                #pragma unroll
                for (int reg = 0; reg < 4; ++reg) {
                    const int token = tok0 + tt * 16 + quad * 4 + reg;
                    dst[(size_t)(b * NTOK + token) * DQK + wr] = f2bf(acc[j][tt][reg]);
                }
        }
    }
    // ---- per-batch max||k||^2 (wave 0: acc[2],acc[3] = K dims 0..31) ----
    if (wave == 0) {
        #pragma unroll
        for (int tt = 0; tt < 2; ++tt) {
            f32x4 kk = acc[2][tt] * acc[2][tt] + acc[3][tt] * acc[3][tt];
            #pragma unroll
            for (int mask = 1; mask <= 8; mask <<= 1)
                #pragma unroll
                for (int reg = 0; reg < 4; ++reg)
                    kk[reg] += __shfl_xor(kk[reg], mask);
            if (low == 0) {
                #pragma unroll
                for (int reg = 0; reg < 4; ++reg)
                    atomicMax(&Mk[b], __builtin_bit_cast(unsigned int, kk[reg]));
            }
        }
    }

    // ---- V epilogue: transpose in re-aliased xs (stride 36 u16) ----
    __syncthreads();                         // all xs fragment reads done
    #pragma unroll
    for (int j = 0; j < 5; ++j) {
        const int rtg = wave * 5 + j;
        if (rtg >= 4) {
            const int c = (rtg - 4) * 16 + low;
            #pragma unroll
            for (int tt = 0; tt < 2; ++tt)
                #pragma unroll
                for (int reg = 0; reg < 4; ++reg)
                    xs[c * 36 + tt * 16 + quad * 4 + reg] = f2bf(acc[j][tt][reg]);
        }
    }
    __syncthreads();
    {
        const int k  = t & 7;
        const int c0 = t >> 3;
        #pragma unroll
        for (int p = 0; p < 8; ++p) {
            const int c = p * 32 + c0;
            const u32x2 v = *reinterpret_cast<const u32x2*>(xs + c * 36 + k * 4);
            *reinterpret_cast<u32x2*>(
                Vh + ((size_t)b * CH + c) * NTOK + tok0 + k * 4) = v;
        }
    }
}

// ---------------------------------------------------------------------------
// Kernel 2: flash attention — EXACT revert to the R1-proposal structure
// (benched Round 2: PASSED, 84.9us). Wave-private double-buffered P,
// barrier-free main loop, S_PHASE(i+1) BEFORE PV(i) (the empirically safe
// order), kf loads inside S_PHASE, setprio around PV, no fences.
// The R3-R7 reorder arc is closed: two ordering theories refuted; R5 showed
// the reorder adds nothing even when fenced-correct (compiler already
// hoists kf loads in this order).
// ---------------------------------------------------------------------------
__global__ __launch_bounds__(512, 2)
void attn(const float* __restrict__ x,
          const unsigned short* __restrict__ Qh,
          const unsigned short* __restrict__ Kh,
          const unsigned short* __restrict__ Vh,
          const unsigned int* __restrict__ Mk,
          float* __restrict__ out)
{
    const int t    = threadIdx.x;
    const int wave = t >> 6;                 // 0..7
    const int kg   = wave & 3;               // keygroup
    const int ch   = wave >> 2;              // channel half (PV only)
    const int lane = t & 63;
    const int low  = lane & 15;
    const int quad = lane >> 4;

    const int beta = blockIdx.x;             // XCD swizzle (perf heuristic)
    const int b    = (beta & 7) >> 1;
    const int q0   = (((beta >> 3) * 2) + (beta & 1)) * 64;

    // dwords: [0,36864) private P, dbuf: buf*18432 + wave*2304 + row*36;
    // [36864,37120) lbuf. Merge slabs (8 x 1408 dw) alias Pbuf0+.
    __shared__ float smem[36864 + 256];
    unsigned int* Pbase = (unsigned int*)smem;
    float* lbuf = smem + 36864;

    const float LOG2E = 1.44269504088896f;

    bf16x8 qfrag[4];
    float  m2[4];
    {
        const float M2 = __builtin_bit_cast(float, Mk[b]);
        #pragma unroll
        for (int j = 0; j < 4; ++j) {
            qfrag[j] = *reinterpret_cast<const bf16x8*>(
                Qh + (size_t)(b * NTOK + q0 + j * 16 + low) * DQK + quad * 8);
            float qn2 = 0.f;
            #pragma unroll
            for (int e = 0; e < 8; ++e) {
                float qv = (float)qfrag[j][e];
                qn2 += qv * qv;
            }
            qn2 += __shfl_xor(qn2, 16);
            qn2 += __shfl_xor(qn2, 32);
            m2[j] = __builtin_sqrtf(qn2 * M2) * (1.02f * LOG2E);
        }
    }

    f32x4 acc[4][8];
    #pragma unroll
    for (int qs = 0; qs < 4; ++qs)
        #pragma unroll
        for (int ct = 0; ct < 8; ++ct) { f32x4 z = {0.f,0.f,0.f,0.f}; acc[qs][ct] = z; }
    float l_s[4] = {0.f, 0.f, 0.f, 0.f};

    const unsigned short* Kb = Kh + (size_t)b * NTOK * DQK;
    const unsigned short* Vb = Vh + (size_t)b * CH * NTOK;

    // S for ALL 4 q-subtiles, own keygroup, into OWN P region (no sharing).
    #define S_PHASE(ii, buf)                                                    \
    {                                                                           \
        const int n0s = ((ii) * 4 + kg) * 64;                                   \
        bf16x8 kf[4];                                                           \
        _Pragma("unroll")                                                       \
        for (int kt = 0; kt < 4; ++kt)                                          \
            kf[kt] = *reinterpret_cast<const bf16x8*>(                          \
                Kb + (size_t)(n0s + kt * 16 + low) * DQK + quad * 8);           \
        _Pragma("unroll")                                                       \
        for (int j = 0; j < 4; ++j) {                                           \
            f32x4 S[4];                                                         \
            _Pragma("unroll")                                                   \
            for (int kt = 0; kt < 4; ++kt) {                                    \
                f32x4 z = {0.f,0.f,0.f,0.f};                                    \
                S[kt] = __builtin_amdgcn_mfma_f32_16x16x32_bf16(kf[kt],         \
                            qfrag[j], z, 0, 0, 0);                              \
            }                                                                   \
            float sum = 0.f;                                                    \
            unsigned int* pq = Pbase + (buf) * 18432 + wave * 2304              \
                               + (j * 16 + low) * 36 + quad * 2;                \
            _Pragma("unroll")                                                   \
            for (int kt = 0; kt < 4; ++kt) {                                    \
                float p0 = __builtin_amdgcn_exp2f(S[kt][0] * LOG2E - m2[j]);    \
                float p1 = __builtin_amdgcn_exp2f(S[kt][1] * LOG2E - m2[j]);    \
                float p2 = __builtin_amdgcn_exp2f(S[kt][2] * LOG2E - m2[j]);    \
                float p3 = __builtin_amdgcn_exp2f(S[kt][3] * LOG2E - m2[j]);    \
                sum += (p0 + p1) + (p2 + p3);                                   \
                u32x2 w2 = {cvt_pk_bf16(p0, p1), cvt_pk_bf16(p2, p3)};          \
                *reinterpret_cast<u32x2*>(pq + kt * 8) = w2;                    \
            }                                                                   \
            l_s[j] += sum;                                                      \
        }                                                                       \
    }

    S_PHASE(0, 0)

    for (int i = 0; i < 16; ++i) {
        if (i < 15) S_PHASE(i + 1, (i + 1) & 1)

        // ---- PV(i) from own Pbuf[i&1] ----
        {
            const int n0 = (i * 4 + kg) * 64;
            const unsigned short* Phh =
                (const unsigned short*)(Pbase + (i & 1) * 18432 + wave * 2304);
            __builtin_amdgcn_s_setprio(1);
            #pragma unroll
            for (int s = 0; s < 2; ++s) {
                bf16x8 pf[4];
                #pragma unroll
                for (int qs = 0; qs < 4; ++qs)
                    pf[qs] = *reinterpret_cast<const bf16x8*>(
                        Phh + (qs * 16 + low) * 72 + s * 32 + quad * 8);
                #pragma unroll
                for (int ct = 0; ct < 8; ++ct) {
                    const bf16x8 vf = *reinterpret_cast<const bf16x8*>(
                        Vb + (size_t)(ch * 128 + ct * 16 + low) * NTOK
                           + n0 + s * 32 + quad * 8);
                    #pragma unroll
                    for (int qs = 0; qs < 4; ++qs)
                        acc[qs][ct] = __builtin_amdgcn_mfma_f32_16x16x32_bf16(
                            vf, pf[qs], acc[qs][ct], 0, 0, 0);
                }
            }
            __builtin_amdgcn_s_setprio(0);
        }
    }
    #undef S_PHASE

    // ---- publish per-keygroup l (each wave computed all 4; publish own 2) ----
    #pragma unroll
    for (int j = 0; j < 4; ++j) {
        l_s[j] += __shfl_xor(l_s[j], 16);
        l_s[j] += __shfl_xor(l_s[j], 32);
    }
    if (quad == 0) {
        #pragma unroll
        for (int jj = 0; jj < 2; ++jj) {
            const int qs = 2 * ch + jj;
            lbuf[kg * 64 + qs * 16 + low] = l_s[qs];
        }
    }
    __syncthreads();   // waves may have drifted; all must be done with P

    // ---- merge 4 kg-partials, 32 channels (16 per ch-half) per round ----
    const int q = t & 63;
    const int u = t >> 6;                    // 0..7
    float invl = 0.f;
    for (int rd = 0; rd < 8; ++rd) {
        #pragma unroll
        for (int qs = 0; qs < 4; ++qs) {
            float* sl = smem + wave * 1408 + (qs * 16 + low) * 22 + quad * 4;
            f32x2 lo = {acc[qs][rd][0], acc[qs][rd][1]};
            f32x2 hi = {acc[qs][rd][2], acc[qs][rd][3]};
            *reinterpret_cast<f32x2*>(sl)     = lo;
            *reinterpret_cast<f32x2*>(sl + 2) = hi;
        }
        __syncthreads();
        if (rd == 0)
            invl = 1.0f / (((lbuf[q] + lbuf[64 + q]) + (lbuf[128 + q] + lbuf[192 + q])));

        #pragma unroll
        for (int p = 0; p < 4; ++p) {
            const int half = p >> 1;
            const int c15  = u * 2 + (p & 1);            // 0..15
            const int wb   = half * 4;
            float O = (smem[(wb + 0) * 1408 + q * 22 + c15]
                     + smem[(wb + 1) * 1408 + q * 22 + c15])
                    + (smem[(wb + 2) * 1408 + q * 22 + c15]
                     + smem[(wb + 3) * 1408 + q * 22 + c15]);
            const int c = half * 128 + rd * 16 + c15;
            const size_t idx = (size_t)(b * CH + c) * NTOK + q0 + q;
            out[idx] = x[idx] + O * invl;
        }
        __syncthreads();
    }
}

extern "C" void kernel_launch(void* const* d_in, const int* in_sizes, int n_in,
                              void* d_out, int out_size, void* d_ws, size_t ws_size,
                              hipStream_t stream) {
    const float* x  = (const float*)d_in[0];
    const float* Wq = (const float*)d_in[1];
    const float* bq = (const float*)d_in[2];
    const float* Wk = (const float*)d_in[3];
    const float* bk = (const float*)d_in[4];
    const float* Wv = (const float*)d_in[5];
    const float* bv = (const float*)d_in[6];
    float* out = (float*)d_out;

    unsigned short* Qh  = (unsigned short*)d_ws;                 // [B,N,32] bf16
    unsigned short* Kh  = Qh  + (size_t)BATCH * NTOK * DQK;      // [B,N,32] bf16
    unsigned short* Vh  = Kh  + (size_t)BATCH * NTOK * DQK;      // [B,C,N] bf16
    unsigned short* Wbf = Vh  + (size_t)BATCH * CH * NTOK;       // [320,256] bf16
    unsigned int*   Mk  = (unsigned int*)(Wbf + 320 * 256);      // [B] max||k||^2

    wconv<<<dim3(80), dim3(256), 0, stream>>>(Wq, Wk, Wv, Wbf, Mk);
    qkv_proj<<<dim3(512), dim3(256), 0, stream>>>(x, bq, bk, bv, Wbf,
                                                  Qh, Kh, Vh, Mk);
    attn<<<dim3(256), dim3(512), 0, stream>>>(x, Qh, Kh, Vh, Mk, out);
}